// Round 5
// baseline (346.283 us; speedup 1.0000x reference)
//
#include <hip/hip_runtime.h>
#include <hip/hip_cooperative_groups.h>
#include <stdint.h>

// B=8, C=256, N=2048. Pipeline (reassociated: x3@(x1^T x2) == (x3@x1^T)@x2):
//   Wcatb = bf16([W1;W2;W3]); W4cat = bf16([W4|W4])
//   featT = bf16(feat^T)                        [8,2048,256]
//   ybf   = Wcat@feat RAW bf16 + row partials   [8,1536,2048]  (GEMM1 epilogue stats)
//   stats = reduce(partials) -> (mu, rsqrt)     [12288]
//   x2T   = normlrelu(x2)^T (fused transpose)   [8,2048,512]
//   Amb   = normlrelu(x3) @ normlrelu(x1)^T     [8,512,512]   (reg-staged norm)
//   x4Ts  = split((normlrelu(x1) - Am@x2n)^T)   [8,2048,1024] bf16 hi|lo
//   out   = lrelu(inorm([W4|W4]@x4Ts))          cooperative: fused z-GEMM+norm,
//           z never hits HBM (acc in regs across grid.sync).

#define LRELU_SLOPE 0.2f
#define EPS_IN 1e-5f

typedef __attribute__((ext_vector_type(8))) short short8v;  // 8 bf16 (4 VGPR)
typedef __attribute__((ext_vector_type(4))) float f32x4;

__device__ __forceinline__ unsigned short f2bf(float f) {
    unsigned int u = __builtin_bit_cast(unsigned int, f);
    u = (u + 0x7fffu + ((u >> 16) & 1u)) >> 16;  // RNE
    return (unsigned short)u;
}
__device__ __forceinline__ float bf2f(unsigned short h) {
    return __builtin_bit_cast(float, (unsigned int)h << 16);
}

typedef const __attribute__((address_space(1))) unsigned int* as1_uint_ptr;
typedef __attribute__((address_space(3))) unsigned int* as3_uint_ptr;

#define GLL16(g, l) __builtin_amdgcn_global_load_lds( \
    (as1_uint_ptr)(const void*)(g), (as3_uint_ptr)(void*)(l), 16, 0, 0)

enum { EP_BF16_STATS = 0, EP_SUB_T_SPLIT_NORM = 1 };

// ---------------------------------------------------------------------------
// TN bf16 MFMA GEMM (128x128 tile, BK=32, 4 waves).
// A:[M][K] k-major, B:[N][K] k-major.
// EP_BF16_STATS: C bf16 [M][N] raw + per-row (sum, sumsq) partials
//                part[(bz*1536 + grow)*gridDim.x + jtile].
// EP_SUB_T_SPLIT_NORM: dv = lrelu((D[m][n]-mu[m])*rs[m]); s = dv - acc;
//                C bf16 [N][ldc]: hi at [n][m], lo at [n][m+ldc/2].
// ---------------------------------------------------------------------------
template<int BM, int BN, int EP>
__global__ __launch_bounds__(256)
void gemm_tn(const unsigned short* __restrict__ A, const unsigned short* __restrict__ B,
             const unsigned short* __restrict__ Dm, void* __restrict__ Cv,
             const float2* __restrict__ stats, float2* __restrict__ part,
             int K, int lda, int ldb, int ldd, int ldc,
             int64_t sA, int64_t sB, int64_t sD, int64_t sC)
{
    constexpr int FM = BM / 32, FN = BN / 32;
    const int bz = blockIdx.z;
    A += sA * bz;
    B += sB * bz;

    const int i0 = blockIdx.y * BM;
    const int j0 = blockIdx.x * BN;

    __shared__ __align__(16) unsigned short As[BM * 32];
    __shared__ __align__(16) unsigned short Bs[BN * 32];

    const int t = threadIdx.x;
    const int w = t >> 6, l = t & 63;
    const int wr = w >> 1, wc = w & 1;

    f32x4 acc[FM][FN];
#pragma unroll
    for (int fm = 0; fm < FM; ++fm)
#pragma unroll
        for (int fn = 0; fn < FN; ++fn)
            acc[fm][fn] = (f32x4){0.f, 0.f, 0.f, 0.f};

    for (int k0 = 0; k0 < K; k0 += 32) {
        __syncthreads();
#pragma unroll
        for (int q = 0; q < BM / 64; ++q) {
            const int seg = w * (BM / 64) + q;
            const int row = seg * 16 + (l >> 2);
            GLL16(A + (size_t)(i0 + row) * lda + k0 + (l & 3) * 8, &As[seg * 512]);
        }
#pragma unroll
        for (int q = 0; q < BN / 64; ++q) {
            const int seg = w * (BN / 64) + q;
            const int row = seg * 16 + (l >> 2);
            GLL16(B + (size_t)(j0 + row) * ldb + k0 + (l & 3) * 8, &Bs[seg * 512]);
        }
        asm volatile("s_waitcnt vmcnt(0)" ::: "memory");
        __syncthreads();

        short8v a[FM], b[FN];
#pragma unroll
        for (int fm = 0; fm < FM; ++fm)
            a[fm] = *(const short8v*)&As[(wr * (BM / 2) + fm * 16 + (l & 15)) * 32 + (l >> 4) * 8];
#pragma unroll
        for (int fn = 0; fn < FN; ++fn)
            b[fn] = *(const short8v*)&Bs[(wc * (BN / 2) + fn * 16 + (l & 15)) * 32 + (l >> 4) * 8];
#pragma unroll
        for (int fm = 0; fm < FM; ++fm)
#pragma unroll
            for (int fn = 0; fn < FN; ++fn)
                acc[fm][fn] = __builtin_amdgcn_mfma_f32_16x16x32_bf16(a[fm], b[fn], acc[fm][fn], 0, 0, 0);
    }

    const int cr4 = (l >> 4) * 4;
    const int cc = l & 15;

    if constexpr (EP == EP_BF16_STATS) {
        unsigned short* C = (unsigned short*)Cv + sC * bz;
        __shared__ float2 wp[2][BM];
#pragma unroll
        for (int fm = 0; fm < FM; ++fm) {
#pragma unroll
            for (int r = 0; r < 4; ++r) {
                float s = 0.f, q = 0.f;
#pragma unroll
                for (int fn = 0; fn < FN; ++fn) {
                    const float v = acc[fm][fn][r];
                    s += v; q += v * v;
                    C[(size_t)(i0 + wr * (BM / 2) + fm * 16 + cr4 + r) * ldc +
                      (j0 + wc * (BN / 2) + fn * 16 + cc)] = f2bf(v);
                }
#pragma unroll
                for (int m = 1; m < 16; m <<= 1) {
                    s += __shfl_xor(s, m, 64);
                    q += __shfl_xor(q, m, 64);
                }
                if ((l & 15) == 0)
                    wp[wc][wr * (BM / 2) + fm * 16 + cr4 + r] = make_float2(s, q);
            }
        }
        __syncthreads();
        if (t < BM) {
            const float2 p0 = wp[0][t], p1 = wp[1][t];
            part[(size_t)(bz * 1536 + i0 + t) * gridDim.x + blockIdx.x] =
                make_float2(p0.x + p1.x, p0.y + p1.y);
        }
    } else {  // EP_SUB_T_SPLIT_NORM
        const unsigned short* D = Dm + sD * bz;
        unsigned short* C = (unsigned short*)Cv + sC * bz;
#pragma unroll
        for (int fm = 0; fm < FM; ++fm) {
            const int grow0 = i0 + wr * (BM / 2) + fm * 16 + cr4;
            float2 st[4];
#pragma unroll
            for (int r = 0; r < 4; ++r) st[r] = stats[bz * 1536 + grow0 + r];
#pragma unroll
            for (int fn = 0; fn < FN; ++fn) {
                const int gcol = j0 + wc * (BN / 2) + fn * 16 + cc;
                ushort4 hi4, lo4;
#pragma unroll
                for (int r = 0; r < 4; ++r) {
                    float dv = (bf2f(D[(size_t)(grow0 + r) * ldd + gcol]) - st[r].x) * st[r].y;
                    dv = dv >= 0.f ? dv : LRELU_SLOPE * dv;
                    const float sv = dv - acc[fm][fn][r];
                    const unsigned short h = f2bf(sv);
                    ((unsigned short*)&hi4)[r] = h;
                    ((unsigned short*)&lo4)[r] = f2bf(sv - bf2f(h));
                }
                *(ushort4*)&C[(size_t)gcol * ldc + grow0] = hi4;
                *(ushort4*)&C[(size_t)gcol * ldc + (ldc >> 1) + grow0] = lo4;
            }
        }
    }
}

// ---------------------------------------------------------------------------
// reduce partials -> (mu, rsqrt(var+eps)) per row. 12288 rows, 16 jtiles.
// ---------------------------------------------------------------------------
__global__ __launch_bounds__(256)
void reduce_stats(const float2* __restrict__ part, float2* __restrict__ stats)
{
    const int row = blockIdx.x * 256 + threadIdx.x;
    float S = 0.f, Q = 0.f;
#pragma unroll
    for (int j = 0; j < 16; ++j) {
        const float2 p = part[(size_t)row * 16 + j];
        S += p.x; Q += p.y;
    }
    const float mu = S * (1.0f / 2048.0f);
    const float var = Q * (1.0f / 2048.0f) - mu * mu;
    stats[row] = make_float2(mu, rsqrtf(var + EPS_IN));
}

// ---------------------------------------------------------------------------
// normalize + lrelu 8 bf16 and store 16B to LDS/global.
// ---------------------------------------------------------------------------
__device__ __forceinline__ void norm_store8(unsigned short* dst, uint4 v, float2 st)
{
    const unsigned int wd[4] = {v.x, v.y, v.z, v.w};
    unsigned int o[4];
#pragma unroll
    for (int i = 0; i < 4; ++i) {
        float a = __builtin_bit_cast(float, wd[i] << 16);
        float b = __builtin_bit_cast(float, wd[i] & 0xffff0000u);
        a = (a - st.x) * st.y; a = a >= 0.f ? a : LRELU_SLOPE * a;
        b = (b - st.x) * st.y; b = b >= 0.f ? b : LRELU_SLOPE * b;
        o[i] = (unsigned int)f2bf(a) | ((unsigned int)f2bf(b) << 16);
    }
    *(uint4*)dst = make_uint4(o[0], o[1], o[2], o[3]);
}

// ---------------------------------------------------------------------------
// Am = normlrelu(x3) @ normlrelu(x1)^T. BM=128 (x3 rows), BN=64 (x1 rows),
// K=2048 (spatial). Reg-staged loads apply norm+lrelu from stats.
// Grid: (512/64, 512/128, 8) = (8, 4, 8). 256 threads.
// ---------------------------------------------------------------------------
__global__ __launch_bounds__(256)
void gemm_am(const unsigned short* __restrict__ ybf, const float2* __restrict__ stats,
             unsigned short* __restrict__ Amb)
{
    const int bz = blockIdx.z;
    const unsigned short* Yb = ybf + (size_t)bz * 3145728;
    const int i0 = blockIdx.y * 128;  // x3 rows
    const int j0 = blockIdx.x * 64;   // x1 rows

    __shared__ __align__(16) unsigned short As[128 * 32];
    __shared__ __align__(16) unsigned short Bs[64 * 32];

    const int t = threadIdx.x, w = t >> 6, l = t & 63;
    const int wr = w >> 1, wc = w & 1;
    const int lr = l >> 2, lk = (l & 3) * 8;

    const int rA0 = i0 + (w * 2 + 0) * 16 + lr;
    const int rA1 = i0 + (w * 2 + 1) * 16 + lr;
    const int rB  = j0 + w * 16 + lr;
    const float2 stA0 = stats[bz * 1536 + 1024 + rA0];
    const float2 stA1 = stats[bz * 1536 + 1024 + rA1];
    const float2 stB  = stats[bz * 1536 + rB];
    const unsigned short* gA0 = Yb + (size_t)(1024 + rA0) * 2048 + lk;
    const unsigned short* gA1 = Yb + (size_t)(1024 + rA1) * 2048 + lk;
    const unsigned short* gB  = Yb + (size_t)rB * 2048 + lk;

    f32x4 acc[4][2];
#pragma unroll
    for (int fm = 0; fm < 4; ++fm)
#pragma unroll
        for (int fn = 0; fn < 2; ++fn)
            acc[fm][fn] = (f32x4){0.f, 0.f, 0.f, 0.f};

    for (int k0 = 0; k0 < 2048; k0 += 32) {
        const uint4 vA0 = *(const uint4*)(gA0 + k0);
        const uint4 vA1 = *(const uint4*)(gA1 + k0);
        const uint4 vB  = *(const uint4*)(gB + k0);
        __syncthreads();  // prior iteration's LDS reads done
        norm_store8(&As[(w * 2 + 0) * 512 + l * 8], vA0, stA0);
        norm_store8(&As[(w * 2 + 1) * 512 + l * 8], vA1, stA1);
        norm_store8(&Bs[w * 512 + l * 8], vB, stB);
        __syncthreads();

        short8v a[4], b[2];
#pragma unroll
        for (int fm = 0; fm < 4; ++fm)
            a[fm] = *(const short8v*)&As[(wr * 64 + fm * 16 + (l & 15)) * 32 + (l >> 4) * 8];
#pragma unroll
        for (int fn = 0; fn < 2; ++fn)
            b[fn] = *(const short8v*)&Bs[(wc * 32 + fn * 16 + (l & 15)) * 32 + (l >> 4) * 8];
#pragma unroll
        for (int fm = 0; fm < 4; ++fm)
#pragma unroll
            for (int fn = 0; fn < 2; ++fn)
                acc[fm][fn] = __builtin_amdgcn_mfma_f32_16x16x32_bf16(a[fm], b[fn], acc[fm][fn], 0, 0, 0);
    }

    unsigned short* C = Amb + (size_t)bz * 262144;
    const int cr4 = (l >> 4) * 4, cc = l & 15;
#pragma unroll
    for (int fm = 0; fm < 4; ++fm)
#pragma unroll
        for (int fn = 0; fn < 2; ++fn)
#pragma unroll
            for (int r = 0; r < 4; ++r)
                C[(size_t)(i0 + wr * 64 + fm * 16 + cr4 + r) * 512 +
                  (j0 + wc * 32 + fn * 16 + cc)] = f2bf(acc[fm][fn][r]);
}

// ---------------------------------------------------------------------------
// Cooperative z-GEMM + fused final instance-norm.
// z = [W4|W4] @ x4Ts (K=1024), M=256, N=2048 per batch. Grid (16,2,8)=256
// blocks (1/CU guaranteed co-resident). acc stays in regs across grid.sync;
// z never写 to HBM. out = lrelu((z-mu)*rsqrt(var+eps)) fp32.
// ---------------------------------------------------------------------------
__global__ __launch_bounds__(256)
void gemm_z_coop(const unsigned short* __restrict__ A, const unsigned short* __restrict__ Bg,
                 float2* __restrict__ zpart, float* __restrict__ out)
{
    const int bz = blockIdx.z;
    const unsigned short* B = Bg + (size_t)bz * 2097152;
    const int i0 = blockIdx.y * 128;
    const int j0 = blockIdx.x * 128;

    __shared__ __align__(16) unsigned short As[128 * 32];
    __shared__ __align__(16) unsigned short Bs[128 * 32];

    const int t = threadIdx.x, w = t >> 6, l = t & 63;
    const int wr = w >> 1, wc = w & 1;

    f32x4 acc[4][4];
#pragma unroll
    for (int fm = 0; fm < 4; ++fm)
#pragma unroll
        for (int fn = 0; fn < 4; ++fn)
            acc[fm][fn] = (f32x4){0.f, 0.f, 0.f, 0.f};

    for (int k0 = 0; k0 < 1024; k0 += 32) {
        __syncthreads();
#pragma unroll
        for (int q = 0; q < 2; ++q) {
            const int seg = w * 2 + q;
            const int row = seg * 16 + (l >> 2);
            GLL16(A + (size_t)(i0 + row) * 1024 + k0 + (l & 3) * 8, &As[seg * 512]);
            GLL16(B + (size_t)(j0 + row) * 1024 + k0 + (l & 3) * 8, &Bs[seg * 512]);
        }
        asm volatile("s_waitcnt vmcnt(0)" ::: "memory");
        __syncthreads();

        short8v a[4], b[4];
#pragma unroll
        for (int fm = 0; fm < 4; ++fm)
            a[fm] = *(const short8v*)&As[(wr * 64 + fm * 16 + (l & 15)) * 32 + (l >> 4) * 8];
#pragma unroll
        for (int fn = 0; fn < 4; ++fn)
            b[fn] = *(const short8v*)&Bs[(wc * 64 + fn * 16 + (l & 15)) * 32 + (l >> 4) * 8];
#pragma unroll
        for (int fm = 0; fm < 4; ++fm)
#pragma unroll
            for (int fn = 0; fn < 4; ++fn)
                acc[fm][fn] = __builtin_amdgcn_mfma_f32_16x16x32_bf16(a[fm], b[fn], acc[fm][fn], 0, 0, 0);
    }

    const int cr4 = (l >> 4) * 4, cc = l & 15;

    // per-row partial (sum, sumsq) over this block's 128 cols
    __shared__ float2 wp[2][128];
#pragma unroll
    for (int fm = 0; fm < 4; ++fm) {
#pragma unroll
        for (int r = 0; r < 4; ++r) {
            float s = 0.f, q = 0.f;
#pragma unroll
            for (int fn = 0; fn < 4; ++fn) {
                const float v = acc[fm][fn][r];
                s += v; q += v * v;
            }
#pragma unroll
            for (int m = 1; m < 16; m <<= 1) {
                s += __shfl_xor(s, m, 64);
                q += __shfl_xor(q, m, 64);
            }
            if ((l & 15) == 0) wp[wc][wr * 64 + fm * 16 + cr4 + r] = make_float2(s, q);
        }
    }
    __syncthreads();
    if (t < 128) {
        const float2 p0 = wp[0][t], p1 = wp[1][t];
        zpart[((size_t)bz * 256 + i0 + t) * 16 + blockIdx.x] = make_float2(p0.x + p1.x, p0.y + p1.y);
    }
    __threadfence();
    cooperative_groups::this_grid().sync();

    // block-local reduction of its 128 rows' stats
    __shared__ float2 rst[128];
    if (t < 128) {
        float S = 0.f, Q = 0.f;
#pragma unroll
        for (int j = 0; j < 16; ++j) {
            const float2 p = zpart[((size_t)bz * 256 + i0 + t) * 16 + j];
            S += p.x; Q += p.y;
        }
        const float mu = S * (1.0f / 2048.0f);
        const float var = Q * (1.0f / 2048.0f) - mu * mu;
        rst[t] = make_float2(mu, rsqrtf(var + EPS_IN));
    }
    __syncthreads();

    float* O = out + (size_t)bz * 524288;
#pragma unroll
    for (int fm = 0; fm < 4; ++fm) {
        const int lrow0 = wr * 64 + fm * 16 + cr4;
        float2 st[4];
#pragma unroll
        for (int r = 0; r < 4; ++r) st[r] = rst[lrow0 + r];
#pragma unroll
        for (int fn = 0; fn < 4; ++fn) {
            const int gcol = j0 + wc * 64 + fn * 16 + cc;
#pragma unroll
            for (int r = 0; r < 4; ++r) {
                float e = (acc[fm][fn][r] - st[r].x) * st[r].y;
                e = e >= 0.f ? e : LRELU_SLOPE * e;
                O[(size_t)(i0 + lrow0 + r) * 2048 + gcol] = e;
            }
        }
    }
}

// ---------------------------------------------------------------------------
// x2T = normlrelu(x2)^T, bf16. in rows 512..1023 of ybf batch slice.
// Grid: (2048/64, 512/64, 8) = (32, 8, 8).
// ---------------------------------------------------------------------------
__global__ __launch_bounds__(256)
void transpose_norm_x2(const unsigned short* __restrict__ ybf,
                       const float2* __restrict__ stats,
                       unsigned short* __restrict__ x2T)
{
    __shared__ __align__(16) unsigned short tile[64][68];
    const int t = threadIdx.x, bz = blockIdx.z;
    const unsigned short* in = ybf + (size_t)bz * 3145728 + (size_t)512 * 2048;
    unsigned short* outp = x2T + (size_t)bz * 1048576;
    const int r0 = blockIdx.y * 64, c0 = blockIdx.x * 64;
    const int ir = t >> 4, ic = (t & 15) * 4;

#pragma unroll
    for (int q = 0; q < 4; ++q) {
        const int rr = q * 16 + ir;
        const float2 st = stats[bz * 1536 + 512 + r0 + rr];
        const ushort4 v = *(const ushort4*)&in[(size_t)(r0 + rr) * 2048 + c0 + ic];
        const unsigned short vv[4] = {v.x, v.y, v.z, v.w};
#pragma unroll
        for (int j = 0; j < 4; ++j) {
            float e = (bf2f(vv[j]) - st.x) * st.y;
            e = e >= 0.f ? e : LRELU_SLOPE * e;
            tile[rr][ic + j] = f2bf(e);
        }
    }
    __syncthreads();

    const int n = t & 63, kc = (t >> 6) * 16;
    unsigned short* op = outp + (size_t)(c0 + n) * 512 + r0 + kc;
    unsigned int wo[8];
#pragma unroll
    for (int i = 0; i < 8; ++i)
        wo[i] = (unsigned int)tile[kc + 2 * i][n] | ((unsigned int)tile[kc + 2 * i + 1][n] << 16);
    *(uint4*)op       = make_uint4(wo[0], wo[1], wo[2], wo[3]);
    *(uint4*)(op + 8) = make_uint4(wo[4], wo[5], wo[6], wo[7]);
}

// ---------------------------------------------------------------------------
// feat^T with cast: [8,256,2048] f32 -> [8,2048,256] bf16. Grid (32,4,8).
// ---------------------------------------------------------------------------
__global__ __launch_bounds__(256)
void transpose_feat(const float* __restrict__ in, unsigned short* __restrict__ out)
{
    __shared__ __align__(16) unsigned short tile[64][68];
    const int t = threadIdx.x, bz = blockIdx.z;
    const float* ip0 = in + (size_t)bz * 524288;
    unsigned short* outp = out + (size_t)bz * 524288;
    const int r0 = blockIdx.y * 64, c0 = blockIdx.x * 64;
    const int ir = t >> 4, ic = (t & 15) * 4;

#pragma unroll
    for (int q = 0; q < 4; ++q) {
        const int rr = q * 16 + ir;
        const float4 v = *(const float4*)&ip0[(size_t)(r0 + rr) * 2048 + c0 + ic];
        tile[rr][ic + 0] = f2bf(v.x);
        tile[rr][ic + 1] = f2bf(v.y);
        tile[rr][ic + 2] = f2bf(v.z);
        tile[rr][ic + 3] = f2bf(v.w);
    }
    __syncthreads();

    const int n = t & 63, kc = (t >> 6) * 16;
    unsigned short* op = outp + (size_t)(c0 + n) * 256 + r0 + kc;
    unsigned int wo[8];
#pragma unroll
    for (int i = 0; i < 8; ++i)
        wo[i] = (unsigned int)tile[kc + 2 * i][n] | ((unsigned int)tile[kc + 2 * i + 1][n] << 16);
    *(uint4*)op       = make_uint4(wo[0], wo[1], wo[2], wo[3]);
    *(uint4*)(op + 8) = make_uint4(wo[4], wo[5], wo[6], wo[7]);
}

// ---------------------------------------------------------------------------
// W1|W2|W3 -> Wcat bf16 [1536][256]; W4 -> W4cat bf16 [256][1024] = [W4|W4].
// ---------------------------------------------------------------------------
__global__ __launch_bounds__(256)
void cast_weights(const float* __restrict__ W1, const float* __restrict__ W2,
                  const float* __restrict__ W3, const float* __restrict__ W4,
                  unsigned short* __restrict__ Wcatb, unsigned short* __restrict__ W4cat)
{
    const int wsel = blockIdx.x >> 7;
    const int local = ((blockIdx.x & 127) * 256 + threadIdx.x) * 4;
    const float* src = (wsel == 0) ? W1 : (wsel == 1) ? W2 : (wsel == 2) ? W3 : W4;
    const float4 v = *(const float4*)(src + local);
    const ushort4 pk = make_ushort4(f2bf(v.x), f2bf(v.y), f2bf(v.z), f2bf(v.w));
    if (wsel < 3) {
        *(ushort4*)(Wcatb + (size_t)wsel * 131072 + local) = pk;
    } else {
        const int o = local >> 9, c = local & 511;
        *(ushort4*)(W4cat + (size_t)o * 1024 + c)       = pk;
        *(ushort4*)(W4cat + (size_t)o * 1024 + 512 + c) = pk;
    }
}

// ---------------------------------------------------------------------------
extern "C" void kernel_launch(void* const* d_in, const int* in_sizes, int n_in,
                              void* d_out, int out_size, void* d_ws, size_t ws_size,
                              hipStream_t stream)
{
    const float* feat = (const float*)d_in[0];
    const float* W1   = (const float*)d_in[1];
    const float* W2   = (const float*)d_in[2];
    const float* W3   = (const float*)d_in[3];
    const float* W4   = (const float*)d_in[4];
    float* out = (float*)d_out;

    char* w = (char*)d_ws;
    unsigned short* ybf   = (unsigned short*)(w + 0);          // 50331648
    unsigned short* featT = (unsigned short*)(w + 50331648);   //  8388608
    unsigned short* x2T   = (unsigned short*)(w + 58720256);   // 16777216
    unsigned short* Amb   = (unsigned short*)(w + 75497472);   //  4194304
    unsigned short* x4Ts  = (unsigned short*)(w + 79691776);   // 33554432
    unsigned short* Wcatb = (unsigned short*)(w + 113246208);  //   786432
    unsigned short* W4cat = (unsigned short*)(w + 114032640);  //   524288
    float2*         part1 = (float2*)(w + 114556928);          //  1572864
    float2*         stats = (float2*)(w + 116129792);          //    98304
    float2*         zpart = (float2*)(w + 116228096);          //   262144

    cast_weights<<<512, 256, 0, stream>>>(W1, W2, W3, W4, Wcatb, W4cat);

    transpose_feat<<<dim3(32, 4, 8), 256, 0, stream>>>(feat, featT);

    // GEMM1: ybf raw + partials. M=1536 N=2048 K=256.
    gemm_tn<128, 128, EP_BF16_STATS><<<dim3(16, 12, 8), 256, 0, stream>>>(
        Wcatb, featT, nullptr, ybf, nullptr, part1,
        256, 256, 256, 0, 2048, 0, 524288, 0, 3145728);

    reduce_stats<<<48, 256, 0, stream>>>(part1, stats);

    transpose_norm_x2<<<dim3(32, 8, 8), 256, 0, stream>>>(ybf, stats, x2T);

    gemm_am<<<dim3(8, 4, 8), 256, 0, stream>>>(ybf, stats, Amb);

    // x4Ts = split((normlrelu(x1) - Am@x2n)^T). M=512 N=2048 K=512.
    gemm_tn<128, 128, EP_SUB_T_SPLIT_NORM><<<dim3(16, 4, 8), 256, 0, stream>>>(
        Amb, x2T, ybf, x4Ts, stats, nullptr,
        512, 512, 512, 2048, 1024, 262144, 1048576, 3145728, 2097152);

    // cooperative z-GEMM + fused final norm -> out
    {
        const unsigned short* a0 = W4cat;
        const unsigned short* b0 = x4Ts;
        float2* zp = zpart;
        float* o0 = out;
        void* zargs[4] = {&a0, &b0, &zp, &o0};
        hipLaunchCooperativeKernel((const void*)gemm_z_coop, dim3(16, 2, 8),
                                   dim3(256, 1, 1), zargs, 0, stream);
    }
}

// Round 6
// 224.211 us; speedup vs baseline: 1.5445x; 1.5445x over previous
//
#include <hip/hip_runtime.h>
#include <stdint.h>

// B=8, C=256, N=2048. Pipeline (reassociated: x3@(x1^T x2) == (x3@x1^T)@x2):
//   Wcatb = bf16([W1;W2;W3]); W4cat = bf16([W4|W4])
//   featT = bf16(feat^T)                        [8,2048,256]
//   ybf   = Wcat@feat RAW bf16 + row partials   [8,1536,2048]
//   stats = reduce(partials) -> (mu, rsqrt)     [12288]
//   x2T   = normlrelu(x2)^T (fused transpose)   [8,2048,512]
//   x1n3  = normlrelu(x1)|normlrelu(x3)         [8,1024,2048]
//   Amb   = x3n @ x1n^T (bf16)                  [8,512,512]   (proven 64x64, 2 blk/CU)
//   x4Ts  = split((x1n - Am@x2n)^T)             [8,2048,1024] bf16 hi|lo  (aliases ybf)
//   z     = [W4|W4] @ x4Ts (fp32)               [8,256,2048]  (aliases ybf tail)
//   out   = lrelu(inorm(z))
// Lesson from r5: cooperative 1-blk/CU fusion loses 60us to exposed latency;
// every GEMM here runs >=2 blocks/CU with the proven m97-style structure.

#define LRELU_SLOPE 0.2f
#define EPS_IN 1e-5f

typedef __attribute__((ext_vector_type(8))) short short8v;  // 8 bf16 (4 VGPR)
typedef __attribute__((ext_vector_type(4))) float f32x4;

__device__ __forceinline__ unsigned short f2bf(float f) {
    unsigned int u = __builtin_bit_cast(unsigned int, f);
    u = (u + 0x7fffu + ((u >> 16) & 1u)) >> 16;  // RNE
    return (unsigned short)u;
}
__device__ __forceinline__ float bf2f(unsigned short h) {
    return __builtin_bit_cast(float, (unsigned int)h << 16);
}

typedef const __attribute__((address_space(1))) unsigned int* as1_uint_ptr;
typedef __attribute__((address_space(3))) unsigned int* as3_uint_ptr;

#define GLL16(g, l) __builtin_amdgcn_global_load_lds( \
    (as1_uint_ptr)(const void*)(g), (as3_uint_ptr)(void*)(l), 16, 0, 0)

enum { EP_F32 = 0, EP_BF16 = 1, EP_SUB_T_SPLIT = 2, EP_BF16_STATS = 3 };

// ---------------------------------------------------------------------------
// TN bf16 MFMA GEMM. A:[M][K] k-major, B:[N][K] k-major. BK=32, 4 waves (2x2).
// EP_F32:  C fp32 [M][N].
// EP_BF16: C bf16 [M][N].
// EP_SUB_T_SPLIT: s = D[m][n] - acc (D bf16); C bf16 [N][ldc]: hi at [n][m],
//                 lo = bf16(s-hi) at [n][m+ldc/2].
// EP_BF16_STATS: C bf16 raw + per-row (sum,sumsq) partials
//                part[(bz*1536+grow)*gridDim.x + blockIdx.x].
// Grid: (N/BN, M/BM, batch).
// ---------------------------------------------------------------------------
template<int BM, int BN, int EP>
__global__ __launch_bounds__(256)
void gemm_tn(const unsigned short* __restrict__ A, const unsigned short* __restrict__ B,
             const unsigned short* __restrict__ Dm, void* __restrict__ Cv,
             float2* __restrict__ part,
             int K, int lda, int ldb, int ldd, int ldc,
             int64_t sA, int64_t sB, int64_t sD, int64_t sC)
{
    constexpr int FM = BM / 32, FN = BN / 32;
    const int bz = blockIdx.z;
    A += sA * bz;
    B += sB * bz;

    const int i0 = blockIdx.y * BM;
    const int j0 = blockIdx.x * BN;

    __shared__ __align__(16) unsigned short As[BM * 32];
    __shared__ __align__(16) unsigned short Bs[BN * 32];

    const int t = threadIdx.x;
    const int w = t >> 6, l = t & 63;
    const int wr = w >> 1, wc = w & 1;

    f32x4 acc[FM][FN];
#pragma unroll
    for (int fm = 0; fm < FM; ++fm)
#pragma unroll
        for (int fn = 0; fn < FN; ++fn)
            acc[fm][fn] = (f32x4){0.f, 0.f, 0.f, 0.f};

    for (int k0 = 0; k0 < K; k0 += 32) {
        __syncthreads();  // prior iteration's LDS reads done
#pragma unroll
        for (int q = 0; q < BM / 64; ++q) {
            const int seg = w * (BM / 64) + q;
            const int row = seg * 16 + (l >> 2);
            GLL16(A + (size_t)(i0 + row) * lda + k0 + (l & 3) * 8, &As[seg * 512]);
        }
#pragma unroll
        for (int q = 0; q < BN / 64; ++q) {
            const int seg = w * (BN / 64) + q;
            const int row = seg * 16 + (l >> 2);
            GLL16(B + (size_t)(j0 + row) * ldb + k0 + (l & 3) * 8, &Bs[seg * 512]);
        }
        asm volatile("s_waitcnt vmcnt(0)" ::: "memory");
        __syncthreads();

        short8v a[FM], b[FN];
#pragma unroll
        for (int fm = 0; fm < FM; ++fm)
            a[fm] = *(const short8v*)&As[(wr * (BM / 2) + fm * 16 + (l & 15)) * 32 + (l >> 4) * 8];
#pragma unroll
        for (int fn = 0; fn < FN; ++fn)
            b[fn] = *(const short8v*)&Bs[(wc * (BN / 2) + fn * 16 + (l & 15)) * 32 + (l >> 4) * 8];
#pragma unroll
        for (int fm = 0; fm < FM; ++fm)
#pragma unroll
            for (int fn = 0; fn < FN; ++fn)
                acc[fm][fn] = __builtin_amdgcn_mfma_f32_16x16x32_bf16(a[fm], b[fn], acc[fm][fn], 0, 0, 0);
    }

    // C/D frag: col = lane&15, row = (lane>>4)*4 + reg.
    const int cr4 = (l >> 4) * 4;
    const int cc = l & 15;

    if constexpr (EP == EP_F32) {
        float* C = (float*)Cv + sC * bz;
#pragma unroll
        for (int fm = 0; fm < FM; ++fm)
#pragma unroll
            for (int fn = 0; fn < FN; ++fn)
#pragma unroll
                for (int r = 0; r < 4; ++r)
                    C[(size_t)(i0 + wr * (BM / 2) + fm * 16 + cr4 + r) * ldc +
                      (j0 + wc * (BN / 2) + fn * 16 + cc)] = acc[fm][fn][r];
    } else if constexpr (EP == EP_BF16) {
        unsigned short* C = (unsigned short*)Cv + sC * bz;
#pragma unroll
        for (int fm = 0; fm < FM; ++fm)
#pragma unroll
            for (int fn = 0; fn < FN; ++fn)
#pragma unroll
                for (int r = 0; r < 4; ++r)
                    C[(size_t)(i0 + wr * (BM / 2) + fm * 16 + cr4 + r) * ldc +
                      (j0 + wc * (BN / 2) + fn * 16 + cc)] = f2bf(acc[fm][fn][r]);
    } else if constexpr (EP == EP_SUB_T_SPLIT) {
        const unsigned short* D = Dm + sD * bz;
        unsigned short* C = (unsigned short*)Cv + sC * bz;
#pragma unroll
        for (int fm = 0; fm < FM; ++fm) {
            const int grow0 = i0 + wr * (BM / 2) + fm * 16 + cr4;
#pragma unroll
            for (int fn = 0; fn < FN; ++fn) {
                const int gcol = j0 + wc * (BN / 2) + fn * 16 + cc;
                ushort4 hi4, lo4;
#pragma unroll
                for (int r = 0; r < 4; ++r) {
                    const float sv = bf2f(D[(size_t)(grow0 + r) * ldd + gcol]) - acc[fm][fn][r];
                    const unsigned short h = f2bf(sv);
                    ((unsigned short*)&hi4)[r] = h;
                    ((unsigned short*)&lo4)[r] = f2bf(sv - bf2f(h));
                }
                *(ushort4*)&C[(size_t)gcol * ldc + grow0] = hi4;
                *(ushort4*)&C[(size_t)gcol * ldc + (ldc >> 1) + grow0] = lo4;
            }
        }
    } else {  // EP_BF16_STATS
        unsigned short* C = (unsigned short*)Cv + sC * bz;
        __shared__ float2 wp[2][BM];
#pragma unroll
        for (int fm = 0; fm < FM; ++fm) {
#pragma unroll
            for (int r = 0; r < 4; ++r) {
                float s = 0.f, q = 0.f;
#pragma unroll
                for (int fn = 0; fn < FN; ++fn) {
                    const float v = acc[fm][fn][r];
                    s += v; q += v * v;
                    C[(size_t)(i0 + wr * (BM / 2) + fm * 16 + cr4 + r) * ldc +
                      (j0 + wc * (BN / 2) + fn * 16 + cc)] = f2bf(v);
                }
#pragma unroll
                for (int m = 1; m < 16; m <<= 1) {
                    s += __shfl_xor(s, m, 64);
                    q += __shfl_xor(q, m, 64);
                }
                if ((l & 15) == 0)
                    wp[wc][wr * (BM / 2) + fm * 16 + cr4 + r] = make_float2(s, q);
            }
        }
        __syncthreads();
        if (t < BM) {
            const float2 p0 = wp[0][t], p1 = wp[1][t];
            part[(size_t)(bz * 1536 + i0 + t) * gridDim.x + blockIdx.x] =
                make_float2(p0.x + p1.x, p0.y + p1.y);
        }
    }
}

// ---------------------------------------------------------------------------
// reduce partials -> (mu, rsqrt(var+eps)) per row. 12288 rows x 16 jtiles.
// ---------------------------------------------------------------------------
__global__ __launch_bounds__(256)
void reduce_stats(const float2* __restrict__ part, float2* __restrict__ stats)
{
    const int row = blockIdx.x * 256 + threadIdx.x;
    float S = 0.f, Q = 0.f;
#pragma unroll
    for (int j = 0; j < 16; ++j) {
        const float2 p = part[(size_t)row * 16 + j];
        S += p.x; Q += p.y;
    }
    const float mu = S * (1.0f / 2048.0f);
    const float var = Q * (1.0f / 2048.0f) - mu * mu;
    stats[row] = make_float2(mu, rsqrtf(var + EPS_IN));
}

// normalize + lrelu 8 bf16 packed in uint4 -> uint4
__device__ __forceinline__ uint4 norm8(uint4 v, float2 st)
{
    const unsigned int wd[4] = {v.x, v.y, v.z, v.w};
    unsigned int o[4];
#pragma unroll
    for (int i = 0; i < 4; ++i) {
        float a = __builtin_bit_cast(float, wd[i] << 16);
        float b = __builtin_bit_cast(float, wd[i] & 0xffff0000u);
        a = (a - st.x) * st.y; a = a >= 0.f ? a : LRELU_SLOPE * a;
        b = (b - st.x) * st.y; b = b >= 0.f ? b : LRELU_SLOPE * b;
        o[i] = (unsigned int)f2bf(a) | ((unsigned int)f2bf(b) << 16);
    }
    return make_uint4(o[0], o[1], o[2], o[3]);
}

// ---------------------------------------------------------------------------
// x1n3: rows 0..511 = normlrelu(x1), rows 512..1023 = normlrelu(x3).
// Grid (1024, 8), 256 thr, one uint4 (8 bf16) per thread -> one row per block.
// ---------------------------------------------------------------------------
__global__ __launch_bounds__(256)
void norm12(const unsigned short* __restrict__ ybf, const float2* __restrict__ stats,
            unsigned short* __restrict__ x1n3)
{
    const int bz = blockIdx.y;
    const int x = blockIdx.x;                       // 0..1023
    const int src = (x < 512) ? x : (x + 512);      // x1 rows or x3 rows
    const float2 st = stats[bz * 1536 + src];
    const uint4 v = ((const uint4*)(ybf + (size_t)bz * 3145728 + (size_t)src * 2048))[threadIdx.x];
    ((uint4*)(x1n3 + (size_t)bz * 2097152 + (size_t)x * 2048))[threadIdx.x] = norm8(v, st);
}

// ---------------------------------------------------------------------------
// x2T = normlrelu(x2)^T, bf16. Reads raw ybf rows 512..1023. Grid (32,8,8).
// ---------------------------------------------------------------------------
__global__ __launch_bounds__(256)
void transpose_norm_x2(const unsigned short* __restrict__ ybf,
                       const float2* __restrict__ stats,
                       unsigned short* __restrict__ x2T)
{
    __shared__ __align__(16) unsigned short tile[64][68];
    const int t = threadIdx.x, bz = blockIdx.z;
    const unsigned short* in = ybf + (size_t)bz * 3145728 + (size_t)512 * 2048;
    unsigned short* outp = x2T + (size_t)bz * 1048576;
    const int r0 = blockIdx.y * 64, c0 = blockIdx.x * 64;
    const int ir = t >> 4, ic = (t & 15) * 4;

#pragma unroll
    for (int q = 0; q < 4; ++q) {
        const int rr = q * 16 + ir;
        const float2 st = stats[bz * 1536 + 512 + r0 + rr];
        const ushort4 v = *(const ushort4*)&in[(size_t)(r0 + rr) * 2048 + c0 + ic];
        const unsigned short vv[4] = {v.x, v.y, v.z, v.w};
#pragma unroll
        for (int j = 0; j < 4; ++j) {
            float e = (bf2f(vv[j]) - st.x) * st.y;
            e = e >= 0.f ? e : LRELU_SLOPE * e;
            tile[rr][ic + j] = f2bf(e);
        }
    }
    __syncthreads();

    const int n = t & 63, kc = (t >> 6) * 16;
    unsigned short* op = outp + (size_t)(c0 + n) * 512 + r0 + kc;
    unsigned int wo[8];
#pragma unroll
    for (int i = 0; i < 8; ++i)
        wo[i] = (unsigned int)tile[kc + 2 * i][n] | ((unsigned int)tile[kc + 2 * i + 1][n] << 16);
    *(uint4*)op       = make_uint4(wo[0], wo[1], wo[2], wo[3]);
    *(uint4*)(op + 8) = make_uint4(wo[4], wo[5], wo[6], wo[7]);
}

// ---------------------------------------------------------------------------
// feat^T with cast: [8,256,2048] f32 -> [8,2048,256] bf16. Grid (32,4,8).
// ---------------------------------------------------------------------------
__global__ __launch_bounds__(256)
void transpose_feat(const float* __restrict__ in, unsigned short* __restrict__ out)
{
    __shared__ __align__(16) unsigned short tile[64][68];
    const int t = threadIdx.x, bz = blockIdx.z;
    const float* ip0 = in + (size_t)bz * 524288;
    unsigned short* outp = out + (size_t)bz * 524288;
    const int r0 = blockIdx.y * 64, c0 = blockIdx.x * 64;
    const int ir = t >> 4, ic = (t & 15) * 4;

#pragma unroll
    for (int q = 0; q < 4; ++q) {
        const int rr = q * 16 + ir;
        const float4 v = *(const float4*)&ip0[(size_t)(r0 + rr) * 2048 + c0 + ic];
        tile[rr][ic + 0] = f2bf(v.x);
        tile[rr][ic + 1] = f2bf(v.y);
        tile[rr][ic + 2] = f2bf(v.z);
        tile[rr][ic + 3] = f2bf(v.w);
    }
    __syncthreads();

    const int n = t & 63, kc = (t >> 6) * 16;
    unsigned short* op = outp + (size_t)(c0 + n) * 256 + r0 + kc;
    unsigned int wo[8];
#pragma unroll
    for (int i = 0; i < 8; ++i)
        wo[i] = (unsigned int)tile[kc + 2 * i][n] | ((unsigned int)tile[kc + 2 * i + 1][n] << 16);
    *(uint4*)op       = make_uint4(wo[0], wo[1], wo[2], wo[3]);
    *(uint4*)(op + 8) = make_uint4(wo[4], wo[5], wo[6], wo[7]);
}

// ---------------------------------------------------------------------------
// Final row instance-norm + leaky-relu, fp32 -> fp32. 1 block per 2048-row.
// ---------------------------------------------------------------------------
__global__ __launch_bounds__(256)
void row_norm_lrelu(const float* __restrict__ in, float* __restrict__ out)
{
    const size_t row = blockIdx.x;
    const float4* p = (const float4*)(in + row * 2048);
    float4* q = (float4*)(out + row * 2048);
    const int t = threadIdx.x;

    float4 v0 = p[t];
    float4 v1 = p[t + 256];

    float s  = v0.x + v0.y + v0.z + v0.w + v1.x + v1.y + v1.z + v1.w;
    float ss = v0.x * v0.x + v0.y * v0.y + v0.z * v0.z + v0.w * v0.w +
               v1.x * v1.x + v1.y * v1.y + v1.z * v1.z + v1.w * v1.w;
#pragma unroll
    for (int off = 32; off > 0; off >>= 1) {
        s  += __shfl_down(s, off, 64);
        ss += __shfl_down(ss, off, 64);
    }
    __shared__ float red[10];
    const int wid = t >> 6;
    if ((t & 63) == 0) { red[wid] = s; red[4 + wid] = ss; }
    __syncthreads();
    if (t == 0) {
        const float S  = red[0] + red[1] + red[2] + red[3];
        const float SS = red[4] + red[5] + red[6] + red[7];
        const float mu = S * (1.0f / 2048.0f);
        const float var = SS * (1.0f / 2048.0f) - mu * mu;
        red[8] = mu;
        red[9] = rsqrtf(var + EPS_IN);
    }
    __syncthreads();
    const float mu = red[8], rs = red[9];
#define NRM(x) { float e = ((x) - mu) * rs; (x) = (e >= 0.0f) ? e : LRELU_SLOPE * e; }
    NRM(v0.x) NRM(v0.y) NRM(v0.z) NRM(v0.w)
    NRM(v1.x) NRM(v1.y) NRM(v1.z) NRM(v1.w)
#undef NRM
    q[t] = v0;
    q[t + 256] = v1;
}

// ---------------------------------------------------------------------------
// W1|W2|W3 -> Wcat bf16 [1536][256]; W4 -> W4cat bf16 [256][1024] = [W4|W4].
// ---------------------------------------------------------------------------
__global__ __launch_bounds__(256)
void cast_weights(const float* __restrict__ W1, const float* __restrict__ W2,
                  const float* __restrict__ W3, const float* __restrict__ W4,
                  unsigned short* __restrict__ Wcatb, unsigned short* __restrict__ W4cat)
{
    const int wsel = blockIdx.x >> 7;
    const int local = ((blockIdx.x & 127) * 256 + threadIdx.x) * 4;
    const float* src = (wsel == 0) ? W1 : (wsel == 1) ? W2 : (wsel == 2) ? W3 : W4;
    const float4 v = *(const float4*)(src + local);
    const ushort4 pk = make_ushort4(f2bf(v.x), f2bf(v.y), f2bf(v.z), f2bf(v.w));
    if (wsel < 3) {
        *(ushort4*)(Wcatb + (size_t)wsel * 131072 + local) = pk;
    } else {
        const int o = local >> 9, c = local & 511;
        *(ushort4*)(W4cat + (size_t)o * 1024 + c)       = pk;
        *(ushort4*)(W4cat + (size_t)o * 1024 + 512 + c) = pk;
    }
}

// ---------------------------------------------------------------------------
extern "C" void kernel_launch(void* const* d_in, const int* in_sizes, int n_in,
                              void* d_out, int out_size, void* d_ws, size_t ws_size,
                              hipStream_t stream)
{
    const float* feat = (const float*)d_in[0];
    const float* W1   = (const float*)d_in[1];
    const float* W2   = (const float*)d_in[2];
    const float* W3   = (const float*)d_in[3];
    const float* W4   = (const float*)d_in[4];
    float* out = (float*)d_out;

    char* w = (char*)d_ws;
    // Region A (0..50.3MB): ybf first; after norm12/transpose_norm_x2 consume
    // it, reused for x4Ts (first 33.5MB) and z (last 16.8MB). 33.5+16.8=50.3.
    unsigned short* ybf   = (unsigned short*)(w + 0);          // 50331648 B
    unsigned short* x4Ts  = (unsigned short*)(w + 0);          // 33554432 B (alias)
    float*          z     = (float*)(w + 33554432);            // 16777216 B (alias)
    unsigned short* featT = (unsigned short*)(w + 50331648);   //  8388608 B
    unsigned short* x2T   = (unsigned short*)(w + 58720256);   // 16777216 B
    unsigned short* x1n3  = (unsigned short*)(w + 75497472);   // 33554432 B
    unsigned short* Amb   = (unsigned short*)(w + 109051904);  //  4194304 B
    unsigned short* Wcatb = (unsigned short*)(w + 113246208);  //   786432 B
    unsigned short* W4cat = (unsigned short*)(w + 114032640);  //   524288 B
    float2*         part1 = (float2*)(w + 114556928);          //  1572864 B
    float2*         stats = (float2*)(w + 116129792);          //    98304 B

    cast_weights<<<512, 256, 0, stream>>>(W1, W2, W3, W4, Wcatb, W4cat);

    transpose_feat<<<dim3(32, 4, 8), 256, 0, stream>>>(feat, featT);

    // GEMM1: ybf raw bf16 + stats partials. M=1536 N=2048 K=256. 6 blk/CU.
    gemm_tn<128, 128, EP_BF16_STATS><<<dim3(16, 12, 8), 256, 0, stream>>>(
        Wcatb, featT, nullptr, ybf, part1,
        256, 256, 256, 0, 2048, 0, 524288, 0, 3145728);

    reduce_stats<<<48, 256, 0, stream>>>(part1, stats);

    // x2T = normlrelu(x2)^T ; x1n3 = normlrelu(x1)|normlrelu(x3)
    transpose_norm_x2<<<dim3(32, 8, 8), 256, 0, stream>>>(ybf, stats, x2T);
    norm12<<<dim3(1024, 8), 256, 0, stream>>>(ybf, stats, x1n3);

    // Am = x3n @ x1n^T : M=512 N=512 K=2048. 512 blocks (2/CU).
    gemm_tn<64, 64, EP_BF16><<<dim3(8, 8, 8), 256, 0, stream>>>(
        x1n3 + 1048576 /*x3n*/, x1n3 /*x1n*/, nullptr, Amb, nullptr,
        2048, 2048, 2048, 0, 512, 2097152, 2097152, 0, 262144);

    // x4Ts = split((x1n - Am@x2n)^T) : M=512 N=2048 K=512. 512 blocks (2/CU).
    // Writes into region A (ybf is dead now).
    gemm_tn<128, 128, EP_SUB_T_SPLIT><<<dim3(16, 4, 8), 256, 0, stream>>>(
        Amb, x2T, x1n3, x4Ts, nullptr,
        512, 512, 512, 2048, 1024, 262144, 1048576, 2097152, 2097152);

    // z = [W4|W4] @ x4Ts : M=256 N=2048 K=1024, fp32. 512 blocks (2/CU).
    gemm_tn<128, 64, EP_F32><<<dim3(32, 2, 8), 256, 0, stream>>>(
        W4cat, x4Ts, nullptr, z, nullptr,
        1024, 1024, 1024, 0, 2048, 0, 2097152, 0, 524288);

    // out = lrelu(inorm(z))
    row_norm_lrelu<<<2048, 256, 0, stream>>>(z, out);
}

// Round 8
// 210.449 us; speedup vs baseline: 1.6454x; 1.0654x over previous
//
#include <hip/hip_runtime.h>
#include <stdint.h>

// B=8, C=256, N=2048. Pipeline (reassociated: x3@(x1^T x2) == (x3@x1^T)@x2):
//   prep:  Wcatb=bf16([W1;W2;W3]), W4cat=bf16([W4|W4]), featT=bf16(feat^T)
//   ybf   = Wcat@feat RAW bf16 + row partials   [8,1536,2048]
//   stats = reduce(partials) -> (mu, rsqrt)     [12288]
//   normx: x2T = normlrelu(x2)^T  [8,2048,512]; x1n3 = nl(x1)|nl(x3) [8,1024,2048]
//   Amb   = x3n @ x1n^T (bf16)                  [8,512,512]
//   x4Ts  = split((x1n - Am@x2n)^T)             [8,2048,1024] bf16 hi|lo (aliases ybf)
//   z     = [W4|W4] @ x4Ts (fp32)               [8,256,2048]  (aliases ybf tail)
//   out   = lrelu(inorm(z))
// r5 lesson: >=2 blocks/CU beats fusion-into-load-path. r7 change: GEMM K-loop
// is 2-phase double-buffered (STAGE(next) || compute(cur), ONE sync per step)
// instead of 1-phase drain-before-compute (full latency exposed per step).

#define LRELU_SLOPE 0.2f
#define EPS_IN 1e-5f

typedef __attribute__((ext_vector_type(8))) short short8v;  // 8 bf16 (4 VGPR)
typedef __attribute__((ext_vector_type(4))) float f32x4;

__device__ __forceinline__ unsigned short f2bf(float f) {
    unsigned int u = __builtin_bit_cast(unsigned int, f);
    u = (u + 0x7fffu + ((u >> 16) & 1u)) >> 16;  // RNE
    return (unsigned short)u;
}
__device__ __forceinline__ float bf2f(unsigned short h) {
    return __builtin_bit_cast(float, (unsigned int)h << 16);
}

typedef const __attribute__((address_space(1))) unsigned int* as1_uint_ptr;
typedef __attribute__((address_space(3))) unsigned int* as3_uint_ptr;

#define GLL16(g, l) __builtin_amdgcn_global_load_lds( \
    (as1_uint_ptr)(const void*)(g), (as3_uint_ptr)(void*)(l), 16, 0, 0)

enum { EP_F32 = 0, EP_BF16 = 1, EP_SUB_T_SPLIT = 2, EP_BF16_STATS = 3 };

// ---------------------------------------------------------------------------
// TN bf16 MFMA GEMM, 2-phase double-buffered. A:[M][K] k-major, B:[N][K]
// k-major. BK=32, 4 waves (2x2). Epilogues as in r6. Grid: (N/BN, M/BM, bz).
// ---------------------------------------------------------------------------
template<int BM, int BN, int EP>
__global__ __launch_bounds__(256)
void gemm_tn(const unsigned short* __restrict__ A, const unsigned short* __restrict__ B,
             const unsigned short* __restrict__ Dm, void* __restrict__ Cv,
             float2* __restrict__ part,
             int K, int lda, int ldb, int ldd, int ldc,
             int64_t sA, int64_t sB, int64_t sD, int64_t sC)
{
    constexpr int FM = BM / 32, FN = BN / 32;
    const int bz = blockIdx.z;
    A += sA * bz;
    B += sB * bz;

    const int i0 = blockIdx.y * BM;
    const int j0 = blockIdx.x * BN;

    __shared__ __align__(16) unsigned short As[2][BM * 32];
    __shared__ __align__(16) unsigned short Bs[2][BN * 32];

    const int t = threadIdx.x;
    const int w = t >> 6, l = t & 63;
    const int wr = w >> 1, wc = w & 1;
    const int srow = l >> 2, skq = (l & 3) * 8;  // staging: row-in-seg, k-offset

    f32x4 acc[FM][FN];
#pragma unroll
    for (int fm = 0; fm < FM; ++fm)
#pragma unroll
        for (int fn = 0; fn < FN; ++fn)
            acc[fm][fn] = (f32x4){0.f, 0.f, 0.f, 0.f};

    const int NT = K / 32;

    // prologue: stage tile 0 into buffer 0
#pragma unroll
    for (int q = 0; q < BM / 64; ++q) {
        const int seg = w * (BM / 64) + q;
        GLL16(A + (size_t)(i0 + seg * 16 + srow) * lda + skq, &As[0][seg * 512]);
    }
#pragma unroll
    for (int q = 0; q < BN / 64; ++q) {
        const int seg = w * (BN / 64) + q;
        GLL16(B + (size_t)(j0 + seg * 16 + srow) * ldb + skq, &Bs[0][seg * 512]);
    }
    __syncthreads();  // drains vmcnt(0): tile 0 resident for all waves

    for (int tt = 0; tt < NT; ++tt) {
        const int cur = tt & 1;
        if (tt + 1 < NT) {  // stage next tile into other buffer (flies during compute)
            const int k0 = (tt + 1) * 32;
#pragma unroll
            for (int q = 0; q < BM / 64; ++q) {
                const int seg = w * (BM / 64) + q;
                GLL16(A + (size_t)(i0 + seg * 16 + srow) * lda + k0 + skq, &As[cur ^ 1][seg * 512]);
            }
#pragma unroll
            for (int q = 0; q < BN / 64; ++q) {
                const int seg = w * (BN / 64) + q;
                GLL16(B + (size_t)(j0 + seg * 16 + srow) * ldb + k0 + skq, &Bs[cur ^ 1][seg * 512]);
            }
        }
        short8v a[FM], b[FN];
#pragma unroll
        for (int fm = 0; fm < FM; ++fm)
            a[fm] = *(const short8v*)&As[cur][(wr * (BM / 2) + fm * 16 + (l & 15)) * 32 + (l >> 4) * 8];
#pragma unroll
        for (int fn = 0; fn < FN; ++fn)
            b[fn] = *(const short8v*)&Bs[cur][(wc * (BN / 2) + fn * 16 + (l & 15)) * 32 + (l >> 4) * 8];
#pragma unroll
        for (int fm = 0; fm < FM; ++fm)
#pragma unroll
            for (int fn = 0; fn < FN; ++fn)
                acc[fm][fn] = __builtin_amdgcn_mfma_f32_16x16x32_bf16(a[fm], b[fn], acc[fm][fn], 0, 0, 0);
        __syncthreads();  // ONE drain point: next-tile GLLs done + reads of cur done
    }

    // C/D frag: col = lane&15, row = (lane>>4)*4 + reg.
    const int cr4 = (l >> 4) * 4;
    const int cc = l & 15;

    if constexpr (EP == EP_F32) {
        float* C = (float*)Cv + sC * bz;
#pragma unroll
        for (int fm = 0; fm < FM; ++fm)
#pragma unroll
            for (int fn = 0; fn < FN; ++fn)
#pragma unroll
                for (int r = 0; r < 4; ++r)
                    C[(size_t)(i0 + wr * (BM / 2) + fm * 16 + cr4 + r) * ldc +
                      (j0 + wc * (BN / 2) + fn * 16 + cc)] = acc[fm][fn][r];
    } else if constexpr (EP == EP_BF16) {
        unsigned short* C = (unsigned short*)Cv + sC * bz;
#pragma unroll
        for (int fm = 0; fm < FM; ++fm)
#pragma unroll
            for (int fn = 0; fn < FN; ++fn)
#pragma unroll
                for (int r = 0; r < 4; ++r)
                    C[(size_t)(i0 + wr * (BM / 2) + fm * 16 + cr4 + r) * ldc +
                      (j0 + wc * (BN / 2) + fn * 16 + cc)] = f2bf(acc[fm][fn][r]);
    } else if constexpr (EP == EP_SUB_T_SPLIT) {
        const unsigned short* D = Dm + sD * bz;
        unsigned short* C = (unsigned short*)Cv + sC * bz;
#pragma unroll
        for (int fm = 0; fm < FM; ++fm) {
            const int grow0 = i0 + wr * (BM / 2) + fm * 16 + cr4;
#pragma unroll
            for (int fn = 0; fn < FN; ++fn) {
                const int gcol = j0 + wc * (BN / 2) + fn * 16 + cc;
                ushort4 hi4, lo4;
#pragma unroll
                for (int r = 0; r < 4; ++r) {
                    const float sv = bf2f(D[(size_t)(grow0 + r) * ldd + gcol]) - acc[fm][fn][r];
                    const unsigned short h = f2bf(sv);
                    ((unsigned short*)&hi4)[r] = h;
                    ((unsigned short*)&lo4)[r] = f2bf(sv - bf2f(h));
                }
                *(ushort4*)&C[(size_t)gcol * ldc + grow0] = hi4;
                *(ushort4*)&C[(size_t)gcol * ldc + (ldc >> 1) + grow0] = lo4;
            }
        }
    } else {  // EP_BF16_STATS
        unsigned short* C = (unsigned short*)Cv + sC * bz;
        __shared__ float2 wp[2][BM];
#pragma unroll
        for (int fm = 0; fm < FM; ++fm) {
#pragma unroll
            for (int r = 0; r < 4; ++r) {
                float s = 0.f, q = 0.f;
#pragma unroll
                for (int fn = 0; fn < FN; ++fn) {
                    const float v = acc[fm][fn][r];
                    s += v; q += v * v;
                    C[(size_t)(i0 + wr * (BM / 2) + fm * 16 + cr4 + r) * ldc +
                      (j0 + wc * (BN / 2) + fn * 16 + cc)] = f2bf(v);
                }
#pragma unroll
                for (int m = 1; m < 16; m <<= 1) {
                    s += __shfl_xor(s, m, 64);
                    q += __shfl_xor(q, m, 64);
                }
                if ((l & 15) == 0)
                    wp[wc][wr * (BM / 2) + fm * 16 + cr4 + r] = make_float2(s, q);
            }
        }
        __syncthreads();
        if (t < BM) {
            const float2 p0 = wp[0][t], p1 = wp[1][t];
            part[(size_t)(bz * 1536 + i0 + t) * gridDim.x + blockIdx.x] =
                make_float2(p0.x + p1.x, p0.y + p1.y);
        }
    }
}

// ---------------------------------------------------------------------------
// reduce partials -> (mu, rsqrt(var+eps)) per row. 12288 rows x 16 jtiles.
// ---------------------------------------------------------------------------
__global__ __launch_bounds__(256)
void reduce_stats(const float2* __restrict__ part, float2* __restrict__ stats)
{
    const int row = blockIdx.x * 256 + threadIdx.x;
    float S = 0.f, Q = 0.f;
#pragma unroll
    for (int j = 0; j < 16; ++j) {
        const float2 p = part[(size_t)row * 16 + j];
        S += p.x; Q += p.y;
    }
    const float mu = S * (1.0f / 2048.0f);
    const float var = Q * (1.0f / 2048.0f) - mu * mu;
    stats[row] = make_float2(mu, rsqrtf(var + EPS_IN));
}

// normalize + lrelu 8 bf16 packed in uint4 -> uint4
__device__ __forceinline__ uint4 norm8(uint4 v, float2 st)
{
    const unsigned int wd[4] = {v.x, v.y, v.z, v.w};
    unsigned int o[4];
#pragma unroll
    for (int i = 0; i < 4; ++i) {
        float a = __builtin_bit_cast(float, wd[i] << 16);
        float b = __builtin_bit_cast(float, wd[i] & 0xffff0000u);
        a = (a - st.x) * st.y; a = a >= 0.f ? a : LRELU_SLOPE * a;
        b = (b - st.x) * st.y; b = b >= 0.f ? b : LRELU_SLOPE * b;
        o[i] = (unsigned int)f2bf(a) | ((unsigned int)f2bf(b) << 16);
    }
    return make_uint4(o[0], o[1], o[2], o[3]);
}

// ---------------------------------------------------------------------------
// Merged: blocks [0,2048) = x2T = normlrelu(x2)^T; blocks [2048,10240) =
// x1n3 rows (x1n | x3n). 256 threads both. Branch is block-uniform.
// ---------------------------------------------------------------------------
__global__ __launch_bounds__(256)
void normx(const unsigned short* __restrict__ ybf, const float2* __restrict__ stats,
           unsigned short* __restrict__ x2T, unsigned short* __restrict__ x1n3)
{
    const int b = blockIdx.x;
    const int t = threadIdx.x;
    if (b < 2048) {
        __shared__ __align__(16) unsigned short tile[64][68];
        const int bx = b & 31, by = (b >> 5) & 7, bz = b >> 8;
        const unsigned short* in = ybf + (size_t)bz * 3145728 + (size_t)512 * 2048;
        unsigned short* outp = x2T + (size_t)bz * 1048576;
        const int r0 = by * 64, c0 = bx * 64;
        const int ir = t >> 4, ic = (t & 15) * 4;
#pragma unroll
        for (int q = 0; q < 4; ++q) {
            const int rr = q * 16 + ir;
            const float2 st = stats[bz * 1536 + 512 + r0 + rr];
            const ushort4 v = *(const ushort4*)&in[(size_t)(r0 + rr) * 2048 + c0 + ic];
            const unsigned short vv[4] = {v.x, v.y, v.z, v.w};
#pragma unroll
            for (int j = 0; j < 4; ++j) {
                float e = (bf2f(vv[j]) - st.x) * st.y;
                e = e >= 0.f ? e : LRELU_SLOPE * e;
                tile[rr][ic + j] = f2bf(e);
            }
        }
        __syncthreads();
        const int n = t & 63, kc = (t >> 6) * 16;
        unsigned short* op = outp + (size_t)(c0 + n) * 512 + r0 + kc;
        unsigned int wo[8];
#pragma unroll
        for (int i = 0; i < 8; ++i)
            wo[i] = (unsigned int)tile[kc + 2 * i][n] | ((unsigned int)tile[kc + 2 * i + 1][n] << 16);
        *(uint4*)op       = make_uint4(wo[0], wo[1], wo[2], wo[3]);
        *(uint4*)(op + 8) = make_uint4(wo[4], wo[5], wo[6], wo[7]);
    } else {
        const int r = b - 2048;
        const int x = r & 1023, bz = r >> 10;
        const int src = (x < 512) ? x : (x + 512);  // x1 rows or x3 rows
        const float2 st = stats[bz * 1536 + src];
        const uint4 v = ((const uint4*)(ybf + (size_t)bz * 3145728 + (size_t)src * 2048))[t];
        ((uint4*)(x1n3 + (size_t)bz * 2097152 + (size_t)x * 2048))[t] = norm8(v, st);
    }
}

// ---------------------------------------------------------------------------
// Merged prep: blocks [0,512) cast weights; blocks [512,1536) feat^T->bf16.
// ---------------------------------------------------------------------------
__global__ __launch_bounds__(256)
void prep(const float* __restrict__ W1, const float* __restrict__ W2,
          const float* __restrict__ W3, const float* __restrict__ W4,
          unsigned short* __restrict__ Wcatb, unsigned short* __restrict__ W4cat,
          const float* __restrict__ feat, unsigned short* __restrict__ featT)
{
    const int b = blockIdx.x;
    const int t = threadIdx.x;
    if (b < 512) {
        const int wsel = b >> 7;
        const int local = ((b & 127) * 256 + t) * 4;
        const float* src = (wsel == 0) ? W1 : (wsel == 1) ? W2 : (wsel == 2) ? W3 : W4;
        const float4 v = *(const float4*)(src + local);
        const ushort4 pk = make_ushort4(f2bf(v.x), f2bf(v.y), f2bf(v.z), f2bf(v.w));
        if (wsel < 3) {
            *(ushort4*)(Wcatb + (size_t)wsel * 131072 + local) = pk;
        } else {
            const int o = local >> 9, c = local & 511;
            *(ushort4*)(W4cat + (size_t)o * 1024 + c)       = pk;
            *(ushort4*)(W4cat + (size_t)o * 1024 + 512 + c) = pk;
        }
    } else {
        __shared__ __align__(16) unsigned short tile[64][68];
        const int r = b - 512;
        const int bx = r & 31, by = (r >> 5) & 3, bz = r >> 7;
        const float* ip0 = feat + (size_t)bz * 524288;
        unsigned short* outp = featT + (size_t)bz * 524288;
        const int r0 = by * 64, c0 = bx * 64;
        const int ir = t >> 4, ic = (t & 15) * 4;
#pragma unroll
        for (int q = 0; q < 4; ++q) {
            const int rr = q * 16 + ir;
            const float4 v = *(const float4*)&ip0[(size_t)(r0 + rr) * 2048 + c0 + ic];
            tile[rr][ic + 0] = f2bf(v.x);
            tile[rr][ic + 1] = f2bf(v.y);
            tile[rr][ic + 2] = f2bf(v.z);
            tile[rr][ic + 3] = f2bf(v.w);
        }
        __syncthreads();
        const int n = t & 63, kc = (t >> 6) * 16;
        unsigned short* op = outp + (size_t)(c0 + n) * 256 + r0 + kc;
        unsigned int wo[8];
#pragma unroll
        for (int i = 0; i < 8; ++i)
            wo[i] = (unsigned int)tile[kc + 2 * i][n] | ((unsigned int)tile[kc + 2 * i + 1][n] << 16);
        *(uint4*)op       = make_uint4(wo[0], wo[1], wo[2], wo[3]);
        *(uint4*)(op + 8) = make_uint4(wo[4], wo[5], wo[6], wo[7]);
    }
}

// ---------------------------------------------------------------------------
// Final row instance-norm + leaky-relu, fp32 -> fp32. 1 block per 2048-row.
// ---------------------------------------------------------------------------
__global__ __launch_bounds__(256)
void row_norm_lrelu(const float* __restrict__ in, float* __restrict__ out)
{
    const size_t row = blockIdx.x;
    const float4* p = (const float4*)(in + row * 2048);
    float4* q = (float4*)(out + row * 2048);
    const int t = threadIdx.x;

    float4 v0 = p[t];
    float4 v1 = p[t + 256];

    float s  = v0.x + v0.y + v0.z + v0.w + v1.x + v1.y + v1.z + v1.w;
    float ss = v0.x * v0.x + v0.y * v0.y + v0.z * v0.z + v0.w * v0.w +
               v1.x * v1.x + v1.y * v1.y + v1.z * v1.z + v1.w * v1.w;
#pragma unroll
    for (int off = 32; off > 0; off >>= 1) {
        s  += __shfl_down(s, off, 64);
        ss += __shfl_down(ss, off, 64);
    }
    __shared__ float red[10];
    const int wid = t >> 6;
    if ((t & 63) == 0) { red[wid] = s; red[4 + wid] = ss; }
    __syncthreads();
    if (t == 0) {
        const float S  = red[0] + red[1] + red[2] + red[3];
        const float SS = red[4] + red[5] + red[6] + red[7];
        const float mu = S * (1.0f / 2048.0f);
        const float var = SS * (1.0f / 2048.0f) - mu * mu;
        red[8] = mu;
        red[9] = rsqrtf(var + EPS_IN);
    }
    __syncthreads();
    const float mu = red[8], rs = red[9];
#define NRM(x) { float e = ((x) - mu) * rs; (x) = (e >= 0.0f) ? e : LRELU_SLOPE * e; }
    NRM(v0.x) NRM(v0.y) NRM(v0.z) NRM(v0.w)
    NRM(v1.x) NRM(v1.y) NRM(v1.z) NRM(v1.w)
#undef NRM
    q[t] = v0;
    q[t + 256] = v1;
}

// ---------------------------------------------------------------------------
extern "C" void kernel_launch(void* const* d_in, const int* in_sizes, int n_in,
                              void* d_out, int out_size, void* d_ws, size_t ws_size,
                              hipStream_t stream)
{
    const float* feat = (const float*)d_in[0];
    const float* W1   = (const float*)d_in[1];
    const float* W2   = (const float*)d_in[2];
    const float* W3   = (const float*)d_in[3];
    const float* W4   = (const float*)d_in[4];
    float* out = (float*)d_out;

    char* w = (char*)d_ws;
    // Region A (0..50.3MB): ybf first; after normx consumes it, reused for
    // x4Ts (33.5MB) + z (16.8MB).
    unsigned short* ybf   = (unsigned short*)(w + 0);          // 50331648 B
    unsigned short* x4Ts  = (unsigned short*)(w + 0);          // 33554432 B (alias)
    float*          z     = (float*)(w + 33554432);            // 16777216 B (alias)
    unsigned short* featT = (unsigned short*)(w + 50331648);   //  8388608 B
    unsigned short* x2T   = (unsigned short*)(w + 58720256);   // 16777216 B
    unsigned short* x1n3  = (unsigned short*)(w + 75497472);   // 33554432 B
    unsigned short* Amb   = (unsigned short*)(w + 109051904);  //  4194304 B
    unsigned short* Wcatb = (unsigned short*)(w + 113246208);  //   786432 B
    unsigned short* W4cat = (unsigned short*)(w + 114032640);  //   524288 B
    float2*         part1 = (float2*)(w + 114556928);          //  1572864 B
    float2*         stats = (float2*)(w + 116129792);          //    98304 B

    // prep: weights cast + feat transpose (merged)
    prep<<<1536, 256, 0, stream>>>(W1, W2, W3, W4, Wcatb, W4cat, feat, featT);

    // GEMM1: ybf raw bf16 + stats partials. M=1536 N=2048 K=256.
    gemm_tn<128, 128, EP_BF16_STATS><<<dim3(16, 12, 8), 256, 0, stream>>>(
        Wcatb, featT, nullptr, ybf, part1,
        256, 256, 256, 0, 2048, 0, 524288, 0, 3145728);

    reduce_stats<<<48, 256, 0, stream>>>(part1, stats);

    // x2T + x1n3 (merged)
    normx<<<10240, 256, 0, stream>>>(ybf, stats, x2T, x1n3);

    // Am = x3n @ x1n^T : M=512 N=512 K=2048. 512 blocks (2/CU).
    gemm_tn<64, 64, EP_BF16><<<dim3(8, 8, 8), 256, 0, stream>>>(
        x1n3 + 1048576 /*x3n*/, x1n3 /*x1n*/, nullptr, Amb, nullptr,
        2048, 2048, 2048, 0, 512, 2097152, 2097152, 0, 262144);

    // x4Ts = split((x1n - Am@x2n)^T) : M=512 N=2048 K=512. 512 blocks.
    gemm_tn<128, 128, EP_SUB_T_SPLIT><<<dim3(16, 4, 8), 256, 0, stream>>>(
        Amb, x2T, x1n3, x4Ts, nullptr,
        512, 512, 512, 2048, 1024, 262144, 1048576, 2097152, 2097152);

    // z = [W4|W4] @ x4Ts : M=256 N=2048 K=1024, fp32. 512 blocks.
    gemm_tn<128, 64, EP_F32><<<dim3(32, 2, 8), 256, 0, stream>>>(
        W4cat, x4Ts, nullptr, z, nullptr,
        1024, 1024, 1024, 0, 2048, 0, 2097152, 0, 524288);

    // out = lrelu(inorm(z))
    row_norm_lrelu<<<2048, 256, 0, stream>>>(z, out);
}